// Round 5
// baseline (125.159 us; speedup 1.0000x reference)
//
#include <hip/hip_runtime.h>

// x: [16, 64, 256, 256] f32 in [0,255)
// out = x * ((floor(x/8) != dominant_bin[bc]) * mean[bc])
// dominant_bin from histc binning: clip(floor(x * 32/255), 0, 31), argmax first-tie.
//
// R4 change: pass A batches 8 global loads into registers BEFORE the LDS
// atomics consume them. The atomics are compiler ordering points that
// prevented load hoisting (VGPR_Count was 32 -> ~2 loads in flight, waves
// stalled on vmcnt each iteration). 8-deep MLP/wave x 32 waves/CU should
// saturate the HBM read stream. __launch_bounds__(1024,8) caps VGPR at 64
// so 2 blocks/CU (100% wave occupancy) is preserved.

#define NBINS 32
#define HW 65536          // 256*256
#define NCHAN 1024        // 16*64
#define BT 1024           // threads per block
#define NREP 32           // histogram replicas
#define HSTRIDE 33        // skew: bank(rep*33+b) = (rep+b)&31

typedef float __attribute__((ext_vector_type(4))) fvec4;

__global__ __launch_bounds__(BT, 8) void fused_colormoc_kernel(
    const float* __restrict__ x, float* __restrict__ out)
{
    __shared__ unsigned int hist[NREP * HSTRIDE];   // 4224 B
    __shared__ float ssum[BT / 64];                 // 16 wave sums
    __shared__ float s_mean;
    __shared__ int   s_dom;

    const int bc   = blockIdx.x;
    const int tid  = threadIdx.x;
    const int wave = tid >> 6;
    const int lane = tid & 63;
    const int rep  = tid & 31;

    // zero the 32*33 = 1056 counters
    hist[tid] = 0u;                                   // words 0..1023
    if (tid < NREP * HSTRIDE - BT) hist[BT + tid] = 0u;
    __syncthreads();

    const fvec4* __restrict__ xp =
        (const fvec4*)(x + (size_t)bc * (size_t)HW);
    const float scale = 32.0f / 255.0f;   // same f32 constant as the reference
    unsigned int* __restrict__ h = &hist[rep * HSTRIDE];

    // ---- pass A: histogram + sum, loads batched 8-deep ahead of atomics ----
    float sum = 0.0f;
    #pragma unroll
    for (int c = 0; c < 2; ++c) {
        fvec4 v[8];
        #pragma unroll
        for (int j = 0; j < 8; ++j)
            v[j] = xp[(c * 8 + j) * BT + tid];        // 8 loads in flight
        #pragma unroll
        for (int j = 0; j < 8; ++j) {
            sum += v[j].x + v[j].y + v[j].z + v[j].w;
            int b0 = min(max((int)(v[j].x * scale), 0), NBINS - 1);
            int b1 = min(max((int)(v[j].y * scale), 0), NBINS - 1);
            int b2 = min(max((int)(v[j].z * scale), 0), NBINS - 1);
            int b3 = min(max((int)(v[j].w * scale), 0), NBINS - 1);
            atomicAdd(&h[b0], 1u);
            atomicAdd(&h[b1], 1u);
            atomicAdd(&h[b2], 1u);
            atomicAdd(&h[b3], 1u);
        }
    }

    // wave reduce the sum (wave = 64 lanes)
    for (int off = 32; off > 0; off >>= 1)
        sum += __shfl_down(sum, off);
    if (lane == 0) ssum[wave] = sum;
    __syncthreads();

    // fold the 32 replicas: thread b (b<32) sums bin b across replicas
    if (tid < NBINS) {
        unsigned int c = 0u;
        #pragma unroll
        for (int r = 0; r < NREP; ++r) c += hist[r * HSTRIDE + tid];
        hist[tid] = c;   // reuse front of hist as folded histogram
    }
    __syncthreads();

    if (tid == 0) {
        // argmax with FIRST-occurrence tie-break (jnp.argmax semantics)
        int best = 0;
        unsigned int bestc = hist[0];
        #pragma unroll
        for (int i = 1; i < NBINS; ++i) {
            unsigned int c = hist[i];
            if (c > bestc) { bestc = c; best = i; }
        }
        s_dom = best;
        float s = 0.0f;
        #pragma unroll
        for (int w = 0; w < BT / 64; ++w) s += ssum[w];
        s_mean = s * (1.0f / (float)HW);
    }
    __syncthreads();

    const int   dm = s_dom;
    const float mn = s_mean;

    // ---- pass B: re-read (L3-hot), compute, nontemporal store ----
    fvec4* __restrict__ op = (fvec4*)(out + (size_t)bc * (size_t)HW);
    #pragma unroll
    for (int it = 0; it < 16; ++it) {
        fvec4 v = xp[it * BT + tid];
        fvec4 o;
        // x >= 0 so (int) truncation == floor; x/8 == x*0.125 exactly (pow2)
        o.x = ((int)(v.x * 0.125f) == dm) ? 0.0f : v.x * mn;
        o.y = ((int)(v.y * 0.125f) == dm) ? 0.0f : v.y * mn;
        o.z = ((int)(v.z * 0.125f) == dm) ? 0.0f : v.z * mn;
        o.w = ((int)(v.w * 0.125f) == dm) ? 0.0f : v.w * mn;
        // nontemporal: stream output past L3 (don't evict x's L3 footprint)
        __builtin_nontemporal_store(o, op + it * BT + tid);
    }
}

extern "C" void kernel_launch(void* const* d_in, const int* in_sizes, int n_in,
                              void* d_out, int out_size, void* d_ws, size_t ws_size,
                              hipStream_t stream) {
    const float* x = (const float*)d_in[0];
    float* out = (float*)d_out;

    fused_colormoc_kernel<<<NCHAN, BT, 0, stream>>>(x, out);
}

// Round 6
// 124.229 us; speedup vs baseline: 1.0075x; 1.0075x over previous
//
#include <hip/hip_runtime.h>

// x: [16, 64, 256, 256] f32 in [0,255)
// out = x * ((floor(x/8) != dominant_bin[bc]) * mean[bc])
// dominant: histc binning clip(floor(x*32/255),0,31), argmax first-tie.
//
// R5 change: per-block CHANNEL PIPELINE. Each block owns 4 channels; pass A
// (histogram, HBM read) of channel i is interleaved chunk-by-chunk with
// pass B (apply + nontemporal store, L3-hot read) of channel i-1, so the
// HBM read and write streams run CONCURRENTLY instead of phase-locked.
// Loads are issued ahead of the LDS atomics and pinned with
// sched_barrier(0) (R4's register batch was silently re-serialized,
// VGPR_Count stayed 32).

#define NBINS 32
#define HW 65536          // 256*256
#define NCHAN 1024        // 16*64
#define BT 1024           // threads per block
#define CPB 4             // channels per block
#define NBLK (NCHAN / CPB)    // 256 blocks
#define ITERS (HW / 4 / BT)   // 16 float4-chunks per channel per thread
#define NREP 32           // histogram replicas
#define HSTRIDE 33        // skew

typedef float __attribute__((ext_vector_type(4))) fvec4;

__device__ __forceinline__ void hist4(unsigned int* __restrict__ h,
                                      fvec4 v, float& sum, float scale) {
    sum += v.x + v.y + v.z + v.w;
    int b0 = min(max((int)(v.x * scale), 0), NBINS - 1);
    int b1 = min(max((int)(v.y * scale), 0), NBINS - 1);
    int b2 = min(max((int)(v.z * scale), 0), NBINS - 1);
    int b3 = min(max((int)(v.w * scale), 0), NBINS - 1);
    atomicAdd(&h[b0], 1u);
    atomicAdd(&h[b1], 1u);
    atomicAdd(&h[b2], 1u);
    atomicAdd(&h[b3], 1u);
}

__device__ __forceinline__ fvec4 applyv(fvec4 w, int dm, float mn) {
    fvec4 o;
    // x >= 0: truncation == floor; x/8 == x*0.125 exactly (pow2)
    o.x = ((int)(w.x * 0.125f) == dm) ? 0.0f : w.x * mn;
    o.y = ((int)(w.y * 0.125f) == dm) ? 0.0f : w.y * mn;
    o.z = ((int)(w.z * 0.125f) == dm) ? 0.0f : w.z * mn;
    o.w = ((int)(w.w * 0.125f) == dm) ? 0.0f : w.w * mn;
    return o;
}

__global__ __launch_bounds__(BT) void fused_colormoc_kernel(
    const float* __restrict__ x, float* __restrict__ out)
{
    __shared__ unsigned int hist[NREP * HSTRIDE];   // 4224 B
    __shared__ unsigned int fold[NBINS];
    __shared__ float ssum[BT / 64];
    __shared__ float s_mean;
    __shared__ int   s_dom;

    const int tid  = threadIdx.x;
    const int wave = tid >> 6;
    const int lane = tid & 63;
    const int rep  = tid & 31;
    const int ch0  = blockIdx.x * CPB;

    hist[tid] = 0u;
    if (tid < NREP * HSTRIDE - BT) hist[BT + tid] = 0u;
    __syncthreads();

    const float scale = 32.0f / 255.0f;
    unsigned int* __restrict__ h = &hist[rep * HSTRIDE];

    int   dm_prev = 0;
    float mn_prev = 0.0f;

    for (int c = 0; c < CPB; ++c) {
        const fvec4* __restrict__ xc =
            (const fvec4*)(x + (size_t)(ch0 + c) * HW);
        float sum = 0.0f;

        if (c == 0) {
            // prologue: A only, 4 loads in flight
            #pragma unroll
            for (int it = 0; it < ITERS; it += 4) {
                fvec4 v0 = xc[(it + 0) * BT + tid];
                fvec4 v1 = xc[(it + 1) * BT + tid];
                fvec4 v2 = xc[(it + 2) * BT + tid];
                fvec4 v3 = xc[(it + 3) * BT + tid];
                __builtin_amdgcn_sched_barrier(0);
                hist4(h, v0, sum, scale);
                hist4(h, v1, sum, scale);
                hist4(h, v2, sum, scale);
                hist4(h, v3, sum, scale);
            }
        } else {
            // steady state: A(ch c) interleaved with B(ch c-1)
            const fvec4* __restrict__ xq =
                (const fvec4*)(x + (size_t)(ch0 + c - 1) * HW);
            fvec4* __restrict__ op =
                (fvec4*)(out + (size_t)(ch0 + c - 1) * HW);
            #pragma unroll
            for (int it = 0; it < ITERS; it += 2) {
                // w first: in-order completion lets stores start while v in flight
                fvec4 w0 = xq[(it + 0) * BT + tid];   // L3-hot
                fvec4 w1 = xq[(it + 1) * BT + tid];
                fvec4 v0 = xc[(it + 0) * BT + tid];   // HBM
                fvec4 v1 = xc[(it + 1) * BT + tid];
                __builtin_amdgcn_sched_barrier(0);
                __builtin_nontemporal_store(applyv(w0, dm_prev, mn_prev),
                                            &op[(it + 0) * BT + tid]);
                __builtin_nontemporal_store(applyv(w1, dm_prev, mn_prev),
                                            &op[(it + 1) * BT + tid]);
                hist4(h, v0, sum, scale);
                hist4(h, v1, sum, scale);
            }
        }

        // ---- per-channel reduction: sum, fold replicas, argmax ----
        for (int off = 32; off > 0; off >>= 1)
            sum += __shfl_down(sum, off);
        if (lane == 0) ssum[wave] = sum;
        __syncthreads();

        if (tid < NBINS) {
            unsigned int cc = 0u;
            #pragma unroll
            for (int r = 0; r < NREP; ++r) cc += hist[r * HSTRIDE + tid];
            fold[tid] = cc;
        }
        __syncthreads();

        // re-zero hist for next channel (fold[] already captured)
        hist[tid] = 0u;
        if (tid < NREP * HSTRIDE - BT) hist[BT + tid] = 0u;

        if (tid == 0) {
            // argmax, FIRST-occurrence tie-break (jnp.argmax semantics)
            int best = 0;
            unsigned int bc_ = fold[0];
            #pragma unroll
            for (int i = 1; i < NBINS; ++i) {
                unsigned int q = fold[i];
                if (q > bc_) { bc_ = q; best = i; }
            }
            s_dom = best;
            float s = 0.0f;
            #pragma unroll
            for (int w = 0; w < BT / 64; ++w) s += ssum[w];
            s_mean = s * (1.0f / (float)HW);
        }
        __syncthreads();

        dm_prev = s_dom;
        mn_prev = s_mean;
    }

    // ---- epilogue: B for the last channel ----
    {
        const fvec4* __restrict__ xq =
            (const fvec4*)(x + (size_t)(ch0 + CPB - 1) * HW);
        fvec4* __restrict__ op =
            (fvec4*)(out + (size_t)(ch0 + CPB - 1) * HW);
        #pragma unroll
        for (int it = 0; it < ITERS; it += 4) {
            fvec4 w0 = xq[(it + 0) * BT + tid];
            fvec4 w1 = xq[(it + 1) * BT + tid];
            fvec4 w2 = xq[(it + 2) * BT + tid];
            fvec4 w3 = xq[(it + 3) * BT + tid];
            __builtin_nontemporal_store(applyv(w0, dm_prev, mn_prev),
                                        &op[(it + 0) * BT + tid]);
            __builtin_nontemporal_store(applyv(w1, dm_prev, mn_prev),
                                        &op[(it + 1) * BT + tid]);
            __builtin_nontemporal_store(applyv(w2, dm_prev, mn_prev),
                                        &op[(it + 2) * BT + tid]);
            __builtin_nontemporal_store(applyv(w3, dm_prev, mn_prev),
                                        &op[(it + 3) * BT + tid]);
        }
    }
}

extern "C" void kernel_launch(void* const* d_in, const int* in_sizes, int n_in,
                              void* d_out, int out_size, void* d_ws, size_t ws_size,
                              hipStream_t stream) {
    const float* x = (const float*)d_in[0];
    float* out = (float*)d_out;

    fused_colormoc_kernel<<<NBLK, BT, 0, stream>>>(x, out);
}